// Round 2
// baseline (357.685 us; speedup 1.0000x reference)
//
#include <hip/hip_runtime.h>
#include <math.h>

#define Bq 32
#define Sq 2048
#define Dq 1024
#define Tq 8
#define TILE 64            // S-rows per block in kernel A
#define NT (Sq / TILE)     // 32 tiles per batch row
#define KSLICE 8           // column-slices for kernel B
#define CPS (256 / KSLICE) // 32 float4 columns per slice

typedef float f32x4 __attribute__((ext_vector_type(4)));

// ---------------------------------------------------------------------------
// Kernel A: for each 64-row tile of (b):
//   scores[b,s] = dot(qry[b,:], ctx[b,s,:]) + log(mask[b,s])   (written out)
//   partial[b,tile,:] = sum_{s in tile} exp(scores[s] - m_tile) * ctx[b,s,:]
// 8 waves/block, each owns 8 rows as two 4-row register-resident chunks with
// online max-rescale; cross-wave combine rescales by exp(m_wave - m_tile).
// ctx is read from HBM exactly once (nontemporal: streamed, read-once).
// Grid (NT, B) = (32, 32), block 512.  HBM floor: 268 MB ctx ≈ 43 us.
// ---------------------------------------------------------------------------
__global__ __launch_bounds__(512) void fused_scores_partial_kernel(
    const float* __restrict__ qry, const float* __restrict__ ctx,
    const float* __restrict__ mask, float* __restrict__ scores,
    f32x4* __restrict__ partial)
{
    const int b    = blockIdx.y;
    const int tile = blockIdx.x;
    const int s0   = tile * TILE;
    const int wave = threadIdx.x >> 6;   // 0..7
    const int lane = threadIdx.x & 63;

    __shared__ float wmax[8];
    __shared__ f32x4 buf[8 * 256];       // 32 KB wave-partial exchange

    const f32x4* q4 = (const f32x4*)(qry + (size_t)b * Dq);
    f32x4 q[4];
#pragma unroll
    for (int k = 0; k < 4; ++k) q[k] = q4[lane + 64 * k];

    f32x4 pacc[4];
#pragma unroll
    for (int k = 0; k < 4; ++k) pacc[k] = (f32x4){0.f, 0.f, 0.f, 0.f};
    float mw = -INFINITY;

#pragma unroll
    for (int p = 0; p < 2; ++p) {
        const int sbase = s0 + wave * 8 + p * 4;

        f32x4 c[4][4];
#pragma unroll
        for (int r = 0; r < 4; ++r) {
            const f32x4* c4 = (const f32x4*)(ctx + ((size_t)b * Sq + sbase + r) * Dq);
#pragma unroll
            for (int k = 0; k < 4; ++k)
                c[r][k] = __builtin_nontemporal_load(c4 + lane + 64 * k);
        }

        float sc[4];
#pragma unroll
        for (int r = 0; r < 4; ++r) {
            f32x4 prod = q[0] * c[r][0] + q[1] * c[r][1]
                       + q[2] * c[r][2] + q[3] * c[r][3];
            float acc = (prod.x + prod.y) + (prod.z + prod.w);
#pragma unroll
            for (int off = 1; off < 64; off <<= 1)   // butterfly: all lanes get sum
                acc += __shfl_xor(acc, off, 64);
            const float mk = mask[(size_t)b * Sq + sbase + r];
            acc += (mk == 1.0f) ? 0.0f : logf(mk);   // log(1)=0 exactly
            sc[r] = acc;
            if (lane == 0) scores[(size_t)b * Sq + sbase + r] = acc;
        }

        const float mc = fmaxf(fmaxf(sc[0], sc[1]), fmaxf(sc[2], sc[3]));
        const float mnew = fmaxf(mw, mc);
        const float scale = (p == 0) ? 0.f : expf(mw - mnew); // p==0: pacc is 0
        mw = mnew;
#pragma unroll
        for (int k = 0; k < 4; ++k) pacc[k] = pacc[k] * scale;
#pragma unroll
        for (int r = 0; r < 4; ++r) {
            const float e = expf(sc[r] - mw);
#pragma unroll
            for (int k = 0; k < 4; ++k) pacc[k] += e * c[r][k];
        }
    }

    if (lane == 0) wmax[wave] = mw;
#pragma unroll
    for (int k = 0; k < 4; ++k) buf[wave * 256 + lane + 64 * k] = pacc[k];
    __syncthreads();

    const int t = threadIdx.x;
    if (t < 256) {
        float mt = wmax[0];
#pragma unroll
        for (int w = 1; w < 8; ++w) mt = fmaxf(mt, wmax[w]);
        f32x4 sum = (f32x4){0.f, 0.f, 0.f, 0.f};
#pragma unroll
        for (int w = 0; w < 8; ++w) {
            const float f = expf(wmax[w] - mt);
            sum += f * buf[w * 256 + t];
        }
        partial[((size_t)b * NT + tile) * 256 + t] = sum;
    }
}

// ---------------------------------------------------------------------------
// Kernel B: grid (KSLICE, B) = (8, 32) = 256 blocks x 256 threads.
// Every block redundantly recomputes the cheap per-b stats from the bit-exact
// scores row (m, Z, ftile[], clip list -- 16 KB of L3-hot reads), then owns a
// 32-float4 column slice of summary:
//   summary_slice = sum_tile ftile*partial[tile,slice] - sum_clip g*ctx[s,slice]
// Tile loop split across 8 thread-groups (4 indep loads each) + LDS combine;
// clip rows also distributed across groups. alphas written by slice 0 only.
// ---------------------------------------------------------------------------
__global__ __launch_bounds__(256) void finalize_kernel(
    const float* __restrict__ ctx, const float* __restrict__ scores,
    const float* __restrict__ prevatts, const int* __restrict__ parent_ptr,
    const f32x4* __restrict__ partial, float* __restrict__ alphas,
    f32x4* __restrict__ summary)
{
    const int ks   = blockIdx.x;         // column slice 0..7
    const int b    = blockIdx.y;
    const int t    = threadIdx.x;
    const int wave = t >> 6;
    const int lane = t & 63;

    __shared__ float ssc[Sq];            // 8 KB: staged scores row
    __shared__ float redA[4], redB[4];
    __shared__ float ftile[NT];          // per-tile rescale factor
    __shared__ int   sidx[Sq];           // clipped-row indices (worst case all)
    __shared__ float sg[Sq];             // clipped-row excess alpha-p
    __shared__ f32x4 psum[KSLICE * CPS]; // 4 KB: per-group slice sums
    __shared__ int   scount;

    if (t == 0) scount = 0;

    const float* srow = scores + (size_t)b * Sq;
    float vals[8];
    float m = -INFINITY;
#pragma unroll
    for (int i = 0; i < 8; ++i) {
        float v = srow[t + 256 * i];
        ssc[t + 256 * i] = v;
        vals[i] = v;
        m = fmaxf(m, v);
    }
#pragma unroll
    for (int off = 1; off < 64; off <<= 1)
        m = fmaxf(m, __shfl_xor(m, off, 64));
    if (lane == 0) redA[wave] = m;
    __syncthreads();                       // covers ssc writes + scount init
    m = fmaxf(fmaxf(redA[0], redA[1]), fmaxf(redA[2], redA[3]));

    float sum = 0.f;
#pragma unroll
    for (int i = 0; i < 8; ++i) {
        vals[i] = expf(vals[i] - m);
        sum += vals[i];
    }
#pragma unroll
    for (int off = 1; off < 64; off <<= 1)
        sum += __shfl_xor(sum, off, 64);
    if (lane == 0) redB[wave] = sum;
    __syncthreads();
    sum = (redB[0] + redB[1]) + (redB[2] + redB[3]);
    const float invZ = 1.0f / sum;

    // per-tile rescale factor: exp(m_tile - m) / Z  (m_tile from bit-exact ssc;
    // fmax over the same 64 floats A maxed -> bit-identical to A's tile max)
    if (t < NT) {
        float tm = -INFINITY;
#pragma unroll
        for (int i = 0; i < TILE; ++i) tm = fmaxf(tm, ssc[t * TILE + i]);
        ftile[t] = expf(tm - m) * invZ;
    }

    // alphas (slice 0 only) + compaction of clipped rows (all slices)
    const float* par = prevatts + ((size_t)b * Tq + parent_ptr[b]) * Sq;
#pragma unroll
    for (int i = 0; i < 8; ++i) {
        const int s = t + 256 * i;
        const float a = vals[i] * invZ;
        const float p = par[s];
        if (ks == 0) alphas[(size_t)b * Sq + s] = fminf(p, a);
        const float g = a - p;
        if (g > 0.f) {
            int pos = atomicAdd(&scount, 1);
            sidx[pos] = s;
            sg[pos]  = g;
        }
    }
    __syncthreads();                       // covers ftile, sidx/sg, scount

    // summary slice: columns [ks*CPS, (ks+1)*CPS)
    const int col = t & (CPS - 1);         // 0..31
    const int grp = t >> 5;                // 0..7
    const f32x4* pp = partial + (size_t)b * NT * 256 + ks * CPS;
    f32x4 acc = (f32x4){0.f, 0.f, 0.f, 0.f};
#pragma unroll
    for (int j = 0; j < 4; ++j) {          // group g owns tiles 4g..4g+3
        const int tl = grp * 4 + j;
        acc += ftile[tl] * pp[(size_t)tl * 256 + col];
    }
    // clip correction, distributed across groups
    const int cnt = scount;
    const f32x4* cb = (const f32x4*)(ctx + (size_t)b * Sq * Dq) + ks * CPS;
    for (int i = grp; i < cnt; i += 8) {
        acc -= sg[i] * cb[(size_t)sidx[i] * 256 + col];
    }
    psum[grp * CPS + col] = acc;
    __syncthreads();
    if (grp == 0) {
        f32x4 r = psum[col];
#pragma unroll
        for (int g = 1; g < 8; ++g) r += psum[g * CPS + col];
        summary[b * 256 + ks * CPS + col] = r;
    }
}

extern "C" void kernel_launch(void* const* d_in, const int* in_sizes, int n_in,
                              void* d_out, int out_size, void* d_ws, size_t ws_size,
                              hipStream_t stream)
{
    const float* qry        = (const float*)d_in[0];
    const float* ctx        = (const float*)d_in[1];
    const float* mask       = (const float*)d_in[2];
    const float* prevatts   = (const float*)d_in[3];
    const int*   parent_ptr = (const int*)d_in[4];

    float* out     = (float*)d_out;
    float* alphas  = out;                      // B*S = 65536
    float* summary = out + Bq * Sq;            // B*D = 32768
    float* scores  = out + Bq * Sq + Bq * Dq;  // B*S = 65536

    f32x4* partial = (f32x4*)d_ws;             // B*NT*D floats = 4 MB

    fused_scores_partial_kernel<<<dim3(NT, Bq), 512, 0, stream>>>(
        qry, ctx, mask, scores, partial);
    finalize_kernel<<<dim3(KSLICE, Bq), 256, 0, stream>>>(
        ctx, scores, prevatts, parent_ptr, partial, alphas, (f32x4*)summary);
}